// Round 2
// baseline (995.386 us; speedup 1.0000x reference)
//
#include <hip/hip_runtime.h>

// BiMPNN layer, MI355X. f32 I/O (per reference dtypes), bf16 MFMA internally.
//   agg  = A  @ (h@W^T  + b)  ==  (A @ h) @ W^T  + deg_out * b   (linearity)
//   aggt = A^T@ (h@Wt^T + bt) ==  (A^T@ h) @ Wt^T + deg_in  * bt
// 1) h (f32) -> h_bf16 once
// 2) device-side CSR+CSC build (histogram -> scan -> fill)
// 3) wave-per-(node,dir) register aggregation of h_bf16 -> AH, ATH (bf16)
// 4) fused MFMA GEMM: out = gelu([h|AH|ATH] @ [Ws|W|Wt]^T + combined bias), f32 out

typedef __bf16 bf16;
typedef __bf16 bf16x2 __attribute__((ext_vector_type(2)));
typedef __bf16 bf16x4 __attribute__((ext_vector_type(4)));
typedef __bf16 bf16x8 __attribute__((ext_vector_type(8)));
typedef float  f32x4  __attribute__((ext_vector_type(4)));

#define D 128

__global__ void k_cast(const float* __restrict__ src, bf16* __restrict__ dst, int n4) {
    int i = blockIdx.x * 256 + threadIdx.x;
    if (i < n4) {
        f32x4 v = *(const f32x4*)&src[i * 4];
        bf16x4 o;
        o.x = (bf16)v.x; o.y = (bf16)v.y; o.z = (bf16)v.z; o.w = (bf16)v.w;
        *(bf16x4*)&dst[i * 4] = o;
    }
}

__global__ void k_count(const int* __restrict__ rows, const int* __restrict__ cols,
                        int* __restrict__ cnt_r, int* __restrict__ cnt_c, int E) {
    int e = blockIdx.x * 256 + threadIdx.x;
    if (e < E) {
        atomicAdd(&cnt_r[rows[e]], 1);
        atomicAdd(&cnt_c[cols[e]], 1);
    }
}

// Exclusive scan of cnt -> ptr (N+1) and cursor copy. One 1024-thread block per
// array (blockIdx.x selects rows/cols array). N=100k -> 98 elems/thread.
__global__ __launch_bounds__(1024) void k_scan2(
    const int* __restrict__ cnt_r, int* __restrict__ row_ptr, int* __restrict__ cur_r,
    const int* __restrict__ cnt_c, int* __restrict__ col_ptr, int* __restrict__ cur_c,
    int N) {
    const int* cnt = blockIdx.x ? cnt_c : cnt_r;
    int* ptr = blockIdx.x ? col_ptr : row_ptr;
    int* cur = blockIdx.x ? cur_c : cur_r;
    __shared__ int sums[1024];
    int t = threadIdx.x;
    int chunk = (N + 1023) >> 10;
    int lo = t * chunk;
    int hi = lo + chunk; if (hi > N) hi = N; if (lo > N) lo = N;
    int s = 0;
    for (int i = lo; i < hi; ++i) s += cnt[i];
    sums[t] = s;
    __syncthreads();
    for (int offs = 1; offs < 1024; offs <<= 1) {
        int v = (t >= offs) ? sums[t - offs] : 0;
        __syncthreads();
        sums[t] += v;
        __syncthreads();
    }
    int run = (t > 0) ? sums[t - 1] : 0;
    for (int i = lo; i < hi; ++i) {
        ptr[i] = run; cur[i] = run;
        run += cnt[i];
    }
    if (t == 1023) ptr[N] = run;
}

__global__ void k_fill(const int* __restrict__ rows, const int* __restrict__ cols,
                       int* __restrict__ cur_r, int* __restrict__ cur_c,
                       int* __restrict__ csr_col, int* __restrict__ csc_row, int E) {
    int e = blockIdx.x * 256 + threadIdx.x;
    if (e < E) {
        int r = rows[e], c = cols[e];
        int p = atomicAdd(&cur_r[r], 1);
        csr_col[p] = c;
        int q = atomicAdd(&cur_c[c], 1);
        csc_row[q] = r;
    }
}

// One wave per (node, direction): lane holds 2 feature dims (bf16x2 = 4B/lane,
// 256B/edge coalesced gather), f32 accumulate, bf16 store.
__global__ void k_agg(const bf16* __restrict__ h,
                      const int* __restrict__ row_ptr, const int* __restrict__ csr_col,
                      const int* __restrict__ col_ptr, const int* __restrict__ csc_row,
                      bf16* __restrict__ AH, bf16* __restrict__ ATH, int N) {
    int wave = threadIdx.x >> 6, lane = threadIdx.x & 63;
    int node = blockIdx.x * 4 + wave;
    if (node >= N) return;
    const int* ptr = blockIdx.y ? col_ptr : row_ptr;
    const int* idx = blockIdx.y ? csc_row : csr_col;
    bf16* dst = blockIdx.y ? ATH : AH;
    const bf16x2* h2 = (const bf16x2*)h;
    int p = ptr[node], end = ptr[node + 1];
    float ax = 0.f, ay = 0.f, bx = 0.f, by = 0.f;
    for (; p + 1 < end; p += 2) {           // unroll x2 for outstanding loads
        int j0 = idx[p], j1 = idx[p + 1];
        bf16x2 v0 = h2[j0 * 64 + lane];
        bf16x2 v1 = h2[j1 * 64 + lane];
        ax += (float)v0.x; ay += (float)v0.y;
        bx += (float)v1.x; by += (float)v1.y;
    }
    if (p < end) {
        int j0 = idx[p];
        bf16x2 v0 = h2[j0 * 64 + lane];
        ax += (float)v0.x; ay += (float)v0.y;
    }
    bf16x2 o; o.x = (bf16)(ax + bx); o.y = (bf16)(ay + by);
    ((bf16x2*)dst)[node * 64 + lane] = o;
}

// Fused GEMM + bias + exact GELU.
// Block: 256 thr = 4 waves (2x2), tile 128 nodes x 128 feats, K=384 in 12 chunks
// of 32. Each wave: 4x4 grid of 16x16x32 bf16 MFMAs.
// Layouts (HW-verified per guide): A frag lane: m=lane&15, k=(lane>>4)*8+j;
// B frag lane: n=lane&15, k=(lane>>4)*8+j; C/D: col=lane&15, row=(lane>>4)*4+r.
// (k-permutation consistency between A and B staging makes exact k order moot.)
__global__ __launch_bounds__(256) void k_gemm(
    const bf16* __restrict__ h, const bf16* __restrict__ AH, const bf16* __restrict__ ATH,
    const float* __restrict__ Ws_w, const float* __restrict__ W_w, const float* __restrict__ Wt_w,
    const float* __restrict__ Ws_b, const float* __restrict__ W_b, const float* __restrict__ Wt_b,
    const int* __restrict__ row_ptr, const int* __restrict__ col_ptr,
    float* __restrict__ out, int N) {
    __shared__ __align__(16) bf16 Ash[128 * 32];
    __shared__ __align__(16) bf16 Bsh[128 * 32];
    int t = threadIdx.x;
    int lane = t & 63;
    int w = t >> 6;
    int wm = (w >> 1) * 64, wn = (w & 1) * 64;
    int m0 = blockIdx.x * 128;

    f32x4 acc[4][4];
#pragma unroll
    for (int i = 0; i < 4; ++i)
#pragma unroll
        for (int j = 0; j < 4; ++j)
            acc[i][j] = (f32x4){0.f, 0.f, 0.f, 0.f};

    for (int kc = 0; kc < 12; ++kc) {
        const bf16*  X  = (kc < 4) ? h    : (kc < 8) ? AH  : ATH;
        const float* Wm = (kc < 4) ? Ws_w : (kc < 8) ? W_w : Wt_w;
        int c0 = (kc & 3) * 32;
        // stage A: 128x32 bf16 tile, 512 x (8-elem/16B) vectors, 2 per thread
#pragma unroll
        for (int r = 0; r < 2; ++r) {
            int v = r * 256 + t;
            int row = v >> 2, seg = v & 3;
            int xr = m0 + row; if (xr >= N) xr = N - 1;  // clamp, stores guarded
            *(bf16x8*)&Ash[row * 32 + seg * 8] =
                *(const bf16x8*)&X[(size_t)xr * D + c0 + seg * 8];
        }
        // stage B: 128x32 f32 tile -> bf16, 1024 float4, 4 per thread
#pragma unroll
        for (int r = 0; r < 4; ++r) {
            int v = r * 256 + t;
            int row = v >> 3, seg = v & 7;
            f32x4 f = *(const f32x4*)&Wm[row * D + c0 + seg * 4];
            bf16x4 o;
            o.x = (bf16)f.x; o.y = (bf16)f.y; o.z = (bf16)f.z; o.w = (bf16)f.w;
            *(bf16x4*)&Bsh[row * 32 + seg * 4] = o;
        }
        __syncthreads();
        int kg = lane >> 4, lr = lane & 15;
        bf16x8 a[4], b[4];
#pragma unroll
        for (int i = 0; i < 4; ++i) {
            a[i] = *(const bf16x8*)&Ash[(wm + i * 16 + lr) * 32 + kg * 8];
            b[i] = *(const bf16x8*)&Bsh[(wn + i * 16 + lr) * 32 + kg * 8];
        }
#pragma unroll
        for (int i = 0; i < 4; ++i)
#pragma unroll
            for (int j = 0; j < 4; ++j)
                acc[i][j] = __builtin_amdgcn_mfma_f32_16x16x32_bf16(
                    a[i], b[j], acc[i][j], 0, 0, 0);
        __syncthreads();
    }

    // epilogue: combined bias (Ws_b + deg_out*W_b + deg_in*Wt_b), exact GELU, f32 out
    int lr = lane & 15, lq = lane >> 4;
#pragma unroll
    for (int i = 0; i < 4; ++i) {
#pragma unroll
        for (int r = 0; r < 4; ++r) {
            int node = m0 + wm + i * 16 + lq * 4 + r;
            if (node >= N) continue;
            int dr = row_ptr[node + 1] - row_ptr[node];
            int dc = col_ptr[node + 1] - col_ptr[node];
            float fdr = (float)dr, fdc = (float)dc;
#pragma unroll
            for (int j = 0; j < 4; ++j) {
                int f = wn + j * 16 + lr;
                float val = acc[i][j][r] + Ws_b[f] + fdr * W_b[f] + fdc * Wt_b[f];
                float g = 0.5f * val * (1.0f + erff(val * 0.70710678118654752f));
                out[(size_t)node * D + f] = g;
            }
        }
    }
}

extern "C" void kernel_launch(void* const* d_in, const int* in_sizes, int n_in,
                              void* d_out, int out_size, void* d_ws, size_t ws_size,
                              hipStream_t stream) {
    const float* h    = (const float*)d_in[0];
    const float* W_w  = (const float*)d_in[1];
    const float* W_b  = (const float*)d_in[2];
    const float* Wt_w = (const float*)d_in[3];
    const float* Wt_b = (const float*)d_in[4];
    const float* Ws_w = (const float*)d_in[5];
    const float* Ws_b = (const float*)d_in[6];
    const int*   rows = (const int*)d_in[7];
    const int*   cols = (const int*)d_in[8];
    float* out = (float*)d_out;

    const int N = in_sizes[0] / D;   // 100000
    const int E = in_sizes[7];       // 1600000

    char* ws = (char*)d_ws;
    size_t off = 0;
    auto take = [&](size_t bytes) -> char* {
        char* p = ws + off;
        off += (bytes + 511) & ~(size_t)511;
        return p;
    };
    bf16* h_bf  = (bf16*)take((size_t)N * D * sizeof(bf16));     // 25.6 MB
    bf16* AH      = (bf16*)take((size_t)N * D * sizeof(bf16));   // 25.6 MB
    bf16* ATH     = (bf16*)take((size_t)N * D * sizeof(bf16));   // 25.6 MB
    int*  cnt     = (int*)take((size_t)2 * N * sizeof(int));     // cnt_r | cnt_c
    int*  row_ptr = (int*)take((size_t)(N + 1) * sizeof(int));
    int*  col_ptr = (int*)take((size_t)(N + 1) * sizeof(int));
    int*  cur_r   = (int*)take((size_t)N * sizeof(int));
    int*  cur_c   = (int*)take((size_t)N * sizeof(int));
    int*  csr_col = (int*)take((size_t)E * sizeof(int));         // 6.4 MB
    int*  csc_row = (int*)take((size_t)E * sizeof(int));         // 6.4 MB
    int*  cnt_r = cnt, *cnt_c = cnt + N;

    hipMemsetAsync(cnt, 0, (size_t)2 * N * sizeof(int), stream);

    int n4 = N * D / 4;
    k_cast<<<(n4 + 255) / 256, 256, 0, stream>>>(h, h_bf, n4);

    int eblocks = (E + 255) / 256;
    k_count<<<eblocks, 256, 0, stream>>>(rows, cols, cnt_r, cnt_c, E);
    k_scan2<<<2, 1024, 0, stream>>>(cnt_r, row_ptr, cur_r, cnt_c, col_ptr, cur_c, N);
    k_fill<<<eblocks, 256, 0, stream>>>(rows, cols, cur_r, cur_c, csr_col, csc_row, E);
    dim3 gagg((N + 3) / 4, 2);
    k_agg<<<gagg, 256, 0, stream>>>(h_bf, row_ptr, csr_col, col_ptr, csc_row, AH, ATH, N);
    k_gemm<<<(N + 127) / 128, 256, 0, stream>>>(h_bf, AH, ATH,
                                                Ws_w, W_w, Wt_w,
                                                Ws_b, W_b, Wt_b,
                                                row_ptr, col_ptr, out, N);
}